// Round 4
// baseline (3435.114 us; speedup 1.0000x reference)
//
#include <hip/hip_runtime.h>

// ---------------------------------------------------------------------------
// MattingSolver CG on MI355X — round 4: latency-oriented iteration rewrite.
//
// R3 post-mortem: lazy-p doubled random gathers (2.95M extra/iter) -> iter
// regressed 72->83us. R4: materialized p (k_it3 back), 4 threads/row with
// width-4 shuffle reduce on all segment loops (serial chain 10->2.5 edges),
// CM pass-B via CSC pull (Lv is L2-resident), Wm/Wc products still pushed to
// row-sorted gath[] (u_all region exceeds per-XCD L2, pulls were misses).
//
// Per iteration (3 kernels):
//   k_it1: Wm/Wc products -> gath (scattered push); CSR: Lv = sum cv (p_i-p_c),
//          rs_cm; pAp = sum diag p^2 + Lv^2 + qf_m + qf_c
//   k_it2: Ap = diag p + rs_cm Lv - csc_pull(Lv) + contiguous_sum(gath);
//          alpha; x += alpha p; r -= alpha Ap; rs_new = r.r   (4 thr/row)
//   k_it3: p = r + beta p
// scal: rs_t at [t], pAp_t at [40+t].
// ---------------------------------------------------------------------------

#define TPB 256

__device__ __forceinline__ float blockReduce256(float v) {
  #pragma unroll
  for (int o = 32; o > 0; o >>= 1) v += __shfl_down(v, o, 64);
  __shared__ float s[4];
  int lane = threadIdx.x & 63, wv = threadIdx.x >> 6;
  if (lane == 0) s[wv] = v;
  __syncthreads();
  return (threadIdx.x == 0) ? (s[0] + s[1] + s[2] + s[3]) : 0.f;
}

// vectors, diag, b, scal, CNT zero, b.b  (grid: 3*Bn)
__global__ void k_init0(const float* __restrict__ KUw, const float* __restrict__ kToUconf,
                        const float* __restrict__ lmbda, const float* __restrict__ known,
                        const float* __restrict__ kToU,
                        float* __restrict__ diag_ku, float* __restrict__ r,
                        float* __restrict__ p0, float* __restrict__ x,
                        int* __restrict__ CNT, float* __restrict__ scal, int N)
{
  int i = blockIdx.x * TPB + threadIdx.x;
  if (i < 80) scal[i] = 0.f;
  if (i < 3 * N) CNT[i] = 0;
  float red = 0.f;
  if (i < N) {
    float dk = KUw[i] * kToUconf[i] + lmbda[0] * known[i];
    diag_ku[i] = dk;
    float b = dk * kToU[i];
    r[i] = b; p0[i] = b; x[i] = 0.f;
    red = b * b;
  }
  float v = blockReduce256(red);
  if (threadIdx.x == 0) atomicAdd(&scal[0], v);
}

// histograms only  (grid: Bz + 2*Bl)
__global__ void k_hist(const int* __restrict__ Wrow, const int* __restrict__ Wcol,
                       const int* __restrict__ LOC_inInd, const int* __restrict__ width_p,
                       const int* __restrict__ IU_inInd, const int* __restrict__ IU_neighInd,
                       int* __restrict__ CNT,
                       int NLOC, int N, int B0, int B1)
{
  int blk = blockIdx.x;
  if (blk < B0) {
    int e = blk * TPB + threadIdx.x;
    atomicAdd(&CNT[Wrow[e]], 1);
    atomicAdd(&CNT[N + Wcol[e]], 1);
  } else if (blk < B1) {
    int k = (blk - B0) * TPB + threadIdx.x;
    int wd = *width_p;
    int base = LOC_inInd[k];
    const int offs[9] = {-1 - wd, -1, -1 + wd, -wd, 0, wd, 1 - wd, 1, 1 + wd};
    #pragma unroll
    for (int a = 0; a < 9; ++a) atomicAdd(&CNT[2 * N + base + offs[a]], 1);
  } else {
    int k = (blk - B1) * TPB + threadIdx.x;
    int r0 = IU_inInd[k];
    #pragma unroll
    for (int j = 0; j < 5; ++j) {
      atomicAdd(&CNT[2 * N + r0], 1);
      atomicAdd(&CNT[2 * N + IU_neighInd[k * 5 + j]], 1);
    }
  }
}

__global__ void k_scan1(const int* __restrict__ CNT, int* __restrict__ OFF,
                        int* __restrict__ bsum, int tot)
{
  __shared__ int s[TPB];
  int gid = blockIdx.x * TPB + threadIdx.x;
  int v = (gid < tot) ? CNT[gid] : 0;
  s[threadIdx.x] = v;
  __syncthreads();
  #pragma unroll
  for (int o = 1; o < TPB; o <<= 1) {
    int t = (threadIdx.x >= o) ? s[threadIdx.x - o] : 0;
    __syncthreads();
    s[threadIdx.x] += t;
    __syncthreads();
  }
  if (gid < tot) OFF[gid] = s[threadIdx.x] - v;
  if (threadIdx.x == TPB - 1) bsum[blockIdx.x] = s[threadIdx.x];
}

__global__ void k_scan2(int* __restrict__ bsum, int nPerArr)  // 3 blocks x 1024
{
  __shared__ int s[1024];
  int base = blockIdx.x * nPerArr;
  int v = (threadIdx.x < nPerArr) ? bsum[base + threadIdx.x] : 0;
  s[threadIdx.x] = v;
  __syncthreads();
  for (int o = 1; o < 1024; o <<= 1) {
    int t = (threadIdx.x >= o) ? s[threadIdx.x - o] : 0;
    __syncthreads();
    s[threadIdx.x] += t;
    __syncthreads();
  }
  if (threadIdx.x < nPerArr) bsum[base + threadIdx.x] = s[threadIdx.x] - v;
}

__global__ void k_scan3(int* __restrict__ OFF, int* __restrict__ CUR,
                        const int* __restrict__ bsum, int tot)
{
  int gid = blockIdx.x * TPB + threadIdx.x;
  if (gid < tot) {
    int o = OFF[gid] + bsum[blockIdx.x];
    OFF[gid] = o;
    CUR[gid] = o;
  }
}

// fill CSR, CSC, and Wm/Wc destination slots
__global__ void k_fill(const float* __restrict__ CMw, const float* __restrict__ Wcm_data,
                       const int* __restrict__ Wrow, const int* __restrict__ Wcol,
                       const int* __restrict__ LOC_inInd, const int* __restrict__ width_p,
                       const int* __restrict__ IU_inInd, const int* __restrict__ IU_neighInd,
                       int* __restrict__ CUR,
                       int* __restrict__ csr_col, float* __restrict__ csr_val,
                       int* __restrict__ csc_row, float* __restrict__ csc_val,
                       int* __restrict__ dIdxWm, int* __restrict__ dIdxA, int* __restrict__ dIdxB,
                       int NLOC, int N, int B0, int B1)
{
  int blk = blockIdx.x;
  if (blk < B0) {
    int e = blk * TPB + threadIdx.x;
    int row = Wrow[e], col = Wcol[e];
    float cv = CMw[row] * Wcm_data[e];
    int pr = atomicAdd(&CUR[row], 1);
    csr_col[pr] = col; csr_val[pr] = cv;
    int pc = atomicAdd(&CUR[N + col], 1);
    csc_row[pc] = row; csc_val[pc] = cv;
  } else if (blk < B1) {
    int k = (blk - B0) * TPB + threadIdx.x;
    int wd = *width_p;
    int base = LOC_inInd[k];
    const int offs[9] = {-1 - wd, -1, -1 + wd, -wd, 0, wd, 1 - wd, 1, 1 + wd};
    #pragma unroll
    for (int a = 0; a < 9; ++a)
      dIdxWm[a * NLOC + k] = atomicAdd(&CUR[2 * N + base + offs[a]], 1);
  } else {
    int k = (blk - B1) * TPB + threadIdx.x;
    int r0 = IU_inInd[k];
    #pragma unroll
    for (int j = 0; j < 5; ++j) {
      int c0 = IU_neighInd[k * 5 + j];
      dIdxA[j * NLOC + k] = atomicAdd(&CUR[2 * N + r0], 1);
      dIdxB[j * NLOC + k] = atomicAdd(&CUR[2 * N + c0], 1);
    }
  }
}

// pass 1: Wm/Wc products -> gath; CSR Lv/rs_cm (4 thr/row); full pAp
// grid: Bl + Bl + 4*Bn
__global__ void k_it1(const float* __restrict__ p,
                      const float* __restrict__ LOC_flows, const int* __restrict__ LOC_inInd,
                      const float* __restrict__ LOCw, const int* __restrict__ width_p,
                      const float* __restrict__ IU_flows, const int* __restrict__ IU_inInd,
                      const int* __restrict__ IU_neighInd, const float* __restrict__ IUw,
                      const float* __restrict__ diag_ku,
                      const int* __restrict__ OFF,
                      const int* __restrict__ csr_col, const float* __restrict__ csr_val,
                      const int* __restrict__ dIdxWm, const int* __restrict__ dIdxA,
                      const int* __restrict__ dIdxB,
                      float* __restrict__ gath,
                      float* __restrict__ Lv, float* __restrict__ rs_cm,
                      float* __restrict__ pAp_t,
                      int NNZ, int NLOC, int N, int B0, int B1)
{
  int blk = blockIdx.x;
  float red = 0.f;
  if (blk < B0) {                       // Wm: u_a = hw sum_b (F+F^T)(p_a - p_b)
    int k = blk * TPB + threadIdx.x;
    int wd = *width_p;
    int base = LOC_inInd[k];
    float hw = 0.5f * LOCw[base];
    const int offs[9] = {-1 - wd, -1, -1 + wd, -wd, 0, wd, 1 - wd, 1, 1 + wd};
    float pv[9];
    #pragma unroll
    for (int a = 0; a < 9; ++a) pv[a] = p[base + offs[a]];
    float Fl[81];
    #pragma unroll
    for (int m = 0; m < 81; ++m) Fl[m] = LOC_flows[(size_t)m * NLOC + k];
    float qf = 0.f;
    #pragma unroll
    for (int a = 0; a < 9; ++a) {
      float u = 0.f;
      #pragma unroll
      for (int b = 0; b < 9; ++b) u += (Fl[b * 9 + a] + Fl[a * 9 + b]) * (pv[a] - pv[b]);
      u *= hw;
      gath[dIdxWm[a * NLOC + k]] = u;
      qf += u * pv[a];
    }
    red = qf;
  } else if (blk < B1) {                // Wc
    int k = (blk - B0) * TPB + threadIdx.x;
    int r0 = IU_inInd[k];
    float hw = 0.5f * IUw[r0];
    float pr = p[r0];
    float qf = 0.f;
    #pragma unroll
    for (int j = 0; j < 5; ++j) {
      float w = hw * IU_flows[k * 5 + j];
      int c0 = IU_neighInd[k * 5 + j];
      float d = pr - p[c0];
      float uA = w * d;
      gath[dIdxA[j * NLOC + k]] = uA;
      gath[dIdxB[j * NLOC + k]] = -uA;
      qf += uA * d;
    }
    red = qf;
  } else {                              // CSR, 4 threads per row
    int g = (blk - B1) * TPB + threadIdx.x;
    int i = g >> 2, t = g & 3;
    float pi = p[i];
    int s = OFF[i];
    int e = (i == N - 1) ? NNZ : OFF[i + 1];
    float acc = 0.f, rs = 0.f;
    for (int q = s + t; q < e; q += 4) {
      float cv = csr_val[q];
      rs += cv;
      acc += cv * (pi - p[csr_col[q]]);
    }
    acc += __shfl_down(acc, 2, 4); acc += __shfl_down(acc, 1, 4);
    rs  += __shfl_down(rs, 2, 4);  rs  += __shfl_down(rs, 1, 4);
    if (t == 0) {
      Lv[i] = acc;
      rs_cm[i] = rs;
      red = diag_ku[i] * pi * pi + acc * acc;
    }
  }
  float v = blockReduce256(red);
  if (threadIdx.x == 0) atomicAdd(pAp_t, v);
}

// pass 2: Ap assembly (4 thr/row) + x/r update + r.r
__global__ void k_it2(float* __restrict__ x, float* __restrict__ r,
                      const float* __restrict__ p, const float* __restrict__ Lv,
                      const float* __restrict__ rs_cm, const float* __restrict__ diag_ku,
                      const int* __restrict__ OFF,
                      const int* __restrict__ csc_row, const float* __restrict__ csc_val,
                      const float* __restrict__ gath,
                      const float* __restrict__ rs_t, const float* __restrict__ pAp_t,
                      float* __restrict__ rs_t1,
                      int NNZ, int NG, int N)
{
  int g = blockIdx.x * TPB + threadIdx.x;
  int i = g >> 2, t = g & 3;
  float alpha = rs_t[0] / pAp_t[0];
  float tg = 0.f;
  {
    int s = OFF[2 * N + i];
    int e = (i == N - 1) ? NG : OFF[2 * N + i + 1];
    for (int q = s + t; q < e; q += 4) tg += gath[q];
  }
  float sc = 0.f;
  {
    int s = OFF[N + i];
    int e = (i == N - 1) ? NNZ : OFF[N + i + 1];
    for (int q = s + t; q < e; q += 4) sc += csc_val[q] * Lv[csc_row[q]];
  }
  tg += __shfl_down(tg, 2, 4); tg += __shfl_down(tg, 1, 4);
  sc += __shfl_down(sc, 2, 4); sc += __shfl_down(sc, 1, 4);
  float red = 0.f;
  if (t == 0) {
    float pi = p[i];
    float Ap = diag_ku[i] * pi + rs_cm[i] * Lv[i] - sc + tg;
    x[i] += alpha * pi;
    float rn = r[i] - alpha * Ap;
    r[i] = rn;
    red = rn * rn;
  }
  float v = blockReduce256(red);
  if (threadIdx.x == 0) atomicAdd(rs_t1, v);
}

__global__ void k_it3(float* __restrict__ p, const float* __restrict__ r,
                      const float* __restrict__ rs_new, const float* __restrict__ rs_old, int N)
{
  int i = blockIdx.x * TPB + threadIdx.x;
  float beta = rs_new[0] / rs_old[0];
  p[i] = r[i] + beta * p[i];
}

extern "C" void kernel_launch(void* const* d_in, const int* in_sizes, int n_in,
                              void* d_out, int out_size, void* d_ws, size_t ws_size,
                              hipStream_t stream)
{
  const float* CMw       = (const float*)d_in[0];
  const float* LOCw      = (const float*)d_in[1];
  const float* IUw       = (const float*)d_in[2];
  const float* KUw       = (const float*)d_in[3];
  const float* lmbda     = (const float*)d_in[4];
  const float* kToUconf  = (const float*)d_in[5];
  const float* known     = (const float*)d_in[6];
  const float* kToU      = (const float*)d_in[7];
  const float* Wcm_data  = (const float*)d_in[8];
  const float* LOC_flows = (const float*)d_in[9];
  const float* IU_flows  = (const float*)d_in[10];
  const int*   Wrow      = (const int*)d_in[11];
  const int*   Wcol      = (const int*)d_in[12];
  const int*   LOC_inInd = (const int*)d_in[13];
  const int*   IU_inInd  = (const int*)d_in[14];
  const int*   IU_neighInd = (const int*)d_in[15];
  const int*   width_p   = (const int*)d_in[16];
  const int CG_STEPS = 30;

  const int N    = in_sizes[0];      // 147456 (% 256 == 0)
  const int NNZ  = in_sizes[8];      // 1474560
  const int NLOC = in_sizes[13];     // 73728
  const int NG   = 19 * NLOC;

  float* x       = (float*)d_out;
  float* r       = (float*)d_ws;
  float* p       = r + N;
  float* Lv      = p + N;
  float* rs_cm   = Lv + N;
  float* diag_ku = rs_cm + N;
  float* csr_val = diag_ku + N;                 // NNZ
  float* csc_val = csr_val + (size_t)NNZ;       // NNZ
  float* gath    = csc_val + (size_t)NNZ;       // NG
  int*   csr_col = (int*)(gath + (size_t)NG);   // NNZ
  int*   csc_row = csr_col + (size_t)NNZ;       // NNZ
  int*   dIdxWm  = csc_row + (size_t)NNZ;       // 9*NLOC
  int*   dIdxA   = dIdxWm + (size_t)9 * NLOC;   // 5*NLOC
  int*   dIdxB   = dIdxA + (size_t)5 * NLOC;    // 5*NLOC
  int*   CNT     = dIdxB + (size_t)5 * NLOC;    // 3N
  int*   OFF     = CNT + (size_t)3 * N;         // 3N
  int*   CUR     = OFF + (size_t)3 * N;         // 3N
  int*   bsum    = CUR + (size_t)3 * N;         // 3*(N/256)
  float* scal    = (float*)(bsum + 3 * (N / TPB));  // rs at [t], pAp at [40+t]

  const int Bn = N / TPB;        // 576
  const int Bz = NNZ / TPB;      // 5760
  const int Bl = NLOC / TPB;     // 288
  const int Z3 = 3 * Bn;

  k_init0<<<Z3, TPB, 0, stream>>>(KUw, kToUconf, lmbda, known, kToU,
                                  diag_ku, r, p, x, CNT, scal, N);
  k_hist<<<Bz + 2 * Bl, TPB, 0, stream>>>(Wrow, Wcol, LOC_inInd, width_p,
                                          IU_inInd, IU_neighInd, CNT,
                                          NLOC, N, Bz, Bz + Bl);
  k_scan1<<<Z3, TPB, 0, stream>>>(CNT, OFF, bsum, 3 * N);
  k_scan2<<<3, 1024, 0, stream>>>(bsum, Bn);
  k_scan3<<<Z3, TPB, 0, stream>>>(OFF, CUR, bsum, 3 * N);
  k_fill<<<Bz + 2 * Bl, TPB, 0, stream>>>(CMw, Wcm_data, Wrow, Wcol,
                                          LOC_inInd, width_p, IU_inInd, IU_neighInd,
                                          CUR, csr_col, csr_val, csc_row, csc_val,
                                          dIdxWm, dIdxA, dIdxB,
                                          NLOC, N, Bz, Bz + Bl);

  for (int t = 0; t < CG_STEPS; ++t) {
    k_it1<<<2 * Bl + 4 * Bn, TPB, 0, stream>>>(
        p, LOC_flows, LOC_inInd, LOCw, width_p,
        IU_flows, IU_inInd, IU_neighInd, IUw,
        diag_ku, OFF, csr_col, csr_val, dIdxWm, dIdxA, dIdxB,
        gath, Lv, rs_cm, scal + 40 + t,
        NNZ, NLOC, N, Bl, 2 * Bl);
    k_it2<<<4 * Bn, TPB, 0, stream>>>(
        x, r, p, Lv, rs_cm, diag_ku, OFF, csc_row, csc_val, gath,
        scal + t, scal + 40 + t, scal + t + 1, NNZ, NG, N);
    if (t + 1 < CG_STEPS)
      k_it3<<<Bn, TPB, 0, stream>>>(p, r, scal + t + 1, scal + t, N);
  }
}

// Round 6
// 2532.075 us; speedup vs baseline: 1.3566x; 1.3566x over previous
//
#include <hip/hip_runtime.h>

// ---------------------------------------------------------------------------
// MattingSolver CG on MI355X — round 6: R2 skeleton, R4 algebra, R5 packing,
// and a workspace layout that FITS (R5 failed on ws overflow: 54.9 MB vs
// proven <=43.4 MB budget; overflow corrupted neighbor buffers -> tripwire).
//
// Layout (39.5 MB): vecs(5N) | csrPk(NNZ int2) | cscPk(NNZ int2) | gIdx(NG)
//   | OFF(3N) | U-region: u_all(NG) aliased over setup-only CNT(3N)+CUR(3N)
//   | bsum | scal.
//
// Per iteration (3 kernels, all proven):
//   k_it1: Wm (direct flows, pair Laplacian form) + Wc -> u_all natural
//          layout; CSR (packed) Lv = sum cv (p_i - p_c), rs_cm;
//          pAp = sum diag p^2 + Lv^2 + qf_m + qf_c
//   k_it2: Ap = diag p + rs_cm Lv - csc_pull(Lv) + gIdx_pull(u_all);
//          alpha; x += alpha p; r -= alpha Ap; rs_new = r.r
//   k_it3: p = r + beta p
// scal: rs_t at [t], pAp_t at [40+t].
// ---------------------------------------------------------------------------

#define TPB 256

__device__ __forceinline__ float blockReduce256(float v) {
  #pragma unroll
  for (int o = 32; o > 0; o >>= 1) v += __shfl_down(v, o, 64);
  __shared__ float s[4];
  int lane = threadIdx.x & 63, wv = threadIdx.x >> 6;
  if (lane == 0) s[wv] = v;
  __syncthreads();
  return (threadIdx.x == 0) ? (s[0] + s[1] + s[2] + s[3]) : 0.f;
}

// vectors, diag, b, scal, CNT zero, b.b  (grid: 3*Bn)
__global__ void k_init0(const float* __restrict__ KUw, const float* __restrict__ kToUconf,
                        const float* __restrict__ lmbda, const float* __restrict__ known,
                        const float* __restrict__ kToU,
                        float* __restrict__ diag_ku, float* __restrict__ r,
                        float* __restrict__ p, float* __restrict__ x,
                        int* __restrict__ CNT, float* __restrict__ scal, int N)
{
  int i = blockIdx.x * TPB + threadIdx.x;
  if (i < 80) scal[i] = 0.f;
  if (i < 3 * N) CNT[i] = 0;
  float red = 0.f;
  if (i < N) {
    float dk = KUw[i] * kToUconf[i] + lmbda[0] * known[i];
    diag_ku[i] = dk;
    float b = dk * kToU[i];
    r[i] = b; p[i] = b; x[i] = 0.f;
    red = b * b;
  }
  float v = blockReduce256(red);
  if (threadIdx.x == 0) atomicAdd(&scal[0], v);
}

// histograms only (4.35M atomics)  (grid: Bz + 2*Bl)
__global__ void k_hist(const int* __restrict__ Wrow, const int* __restrict__ Wcol,
                       const int* __restrict__ LOC_inInd, const int* __restrict__ width_p,
                       const int* __restrict__ IU_inInd, const int* __restrict__ IU_neighInd,
                       int* __restrict__ CNT,
                       int NLOC, int N, int B0, int B1)
{
  int blk = blockIdx.x;
  if (blk < B0) {
    int e = blk * TPB + threadIdx.x;
    atomicAdd(&CNT[Wrow[e]], 1);
    atomicAdd(&CNT[N + Wcol[e]], 1);
  } else if (blk < B1) {
    int k = (blk - B0) * TPB + threadIdx.x;
    int wd = *width_p;
    int base = LOC_inInd[k];
    const int offs[9] = {-1 - wd, -1, -1 + wd, -wd, 0, wd, 1 - wd, 1, 1 + wd};
    #pragma unroll
    for (int a = 0; a < 9; ++a) atomicAdd(&CNT[2 * N + base + offs[a]], 1);
  } else {
    int k = (blk - B1) * TPB + threadIdx.x;
    int r0 = IU_inInd[k];
    #pragma unroll
    for (int j = 0; j < 5; ++j) {
      atomicAdd(&CNT[2 * N + r0], 1);
      atomicAdd(&CNT[2 * N + IU_neighInd[k * 5 + j]], 1);
    }
  }
}

__global__ void k_scan1(const int* __restrict__ CNT, int* __restrict__ OFF,
                        int* __restrict__ bsum, int tot)
{
  __shared__ int s[TPB];
  int gid = blockIdx.x * TPB + threadIdx.x;
  int v = (gid < tot) ? CNT[gid] : 0;
  s[threadIdx.x] = v;
  __syncthreads();
  #pragma unroll
  for (int o = 1; o < TPB; o <<= 1) {
    int t = (threadIdx.x >= o) ? s[threadIdx.x - o] : 0;
    __syncthreads();
    s[threadIdx.x] += t;
    __syncthreads();
  }
  if (gid < tot) OFF[gid] = s[threadIdx.x] - v;
  if (threadIdx.x == TPB - 1) bsum[blockIdx.x] = s[threadIdx.x];
}

__global__ void k_scan2(int* __restrict__ bsum, int nPerArr)  // 3 blocks x 1024
{
  __shared__ int s[1024];
  int base = blockIdx.x * nPerArr;
  int v = (threadIdx.x < nPerArr) ? bsum[base + threadIdx.x] : 0;
  s[threadIdx.x] = v;
  __syncthreads();
  for (int o = 1; o < 1024; o <<= 1) {
    int t = (threadIdx.x >= o) ? s[threadIdx.x - o] : 0;
    __syncthreads();
    s[threadIdx.x] += t;
    __syncthreads();
  }
  if (threadIdx.x < nPerArr) bsum[base + threadIdx.x] = s[threadIdx.x] - v;
}

__global__ void k_scan3(int* __restrict__ OFF, int* __restrict__ CUR,
                        const int* __restrict__ bsum, int tot)
{
  int gid = blockIdx.x * TPB + threadIdx.x;
  if (gid < tot) {
    int o = OFF[gid] + bsum[blockIdx.x];
    OFF[gid] = o;
    CUR[gid] = o;
  }
}

// fill packed CSR/CSC and gather-index list  (grid: Bz + 2*Bl)
__global__ void k_fill(const float* __restrict__ CMw, const float* __restrict__ Wcm_data,
                       const int* __restrict__ Wrow, const int* __restrict__ Wcol,
                       const int* __restrict__ LOC_inInd, const int* __restrict__ width_p,
                       const int* __restrict__ IU_inInd, const int* __restrict__ IU_neighInd,
                       int* __restrict__ CUR,
                       int2* __restrict__ csrPk, int2* __restrict__ cscPk,
                       int* __restrict__ gIdx,
                       int NLOC, int N, int B0, int B1)
{
  int blk = blockIdx.x;
  if (blk < B0) {
    int e = blk * TPB + threadIdx.x;
    int row = Wrow[e], col = Wcol[e];
    int cv = __float_as_int(CMw[row] * Wcm_data[e]);
    int pr = atomicAdd(&CUR[row], 1);
    csrPk[pr] = make_int2(col, cv);
    int pc = atomicAdd(&CUR[N + col], 1);
    cscPk[pc] = make_int2(row, cv);
  } else if (blk < B1) {
    int k = (blk - B0) * TPB + threadIdx.x;
    int wd = *width_p;
    int base = LOC_inInd[k];
    const int offs[9] = {-1 - wd, -1, -1 + wd, -wd, 0, wd, 1 - wd, 1, 1 + wd};
    #pragma unroll
    for (int a = 0; a < 9; ++a) {
      int pos = atomicAdd(&CUR[2 * N + base + offs[a]], 1);
      gIdx[pos] = a * NLOC + k;
    }
  } else {
    int k = (blk - B1) * TPB + threadIdx.x;
    int r0 = IU_inInd[k];
    #pragma unroll
    for (int j = 0; j < 5; ++j) {
      int c0 = IU_neighInd[k * 5 + j];
      int p1 = atomicAdd(&CUR[2 * N + r0], 1);
      gIdx[p1] = 9 * NLOC + j * NLOC + k;    // +w(p_r0 - p_c0) -> row r0
      int p2 = atomicAdd(&CUR[2 * N + c0], 1);
      gIdx[p2] = 14 * NLOC + j * NLOC + k;   // -w(p_r0 - p_c0) -> row c0
    }
  }
}

// pass 1: Wm/Wc products -> u_all (natural layout); CSR Lv/rs_cm; full pAp
// grid: Bl + Bl + Bn
__global__ void k_it1(const float* __restrict__ p,
                      const float* __restrict__ LOC_flows, const int* __restrict__ LOC_inInd,
                      const float* __restrict__ LOCw, const int* __restrict__ width_p,
                      const float* __restrict__ IU_flows, const int* __restrict__ IU_inInd,
                      const int* __restrict__ IU_neighInd, const float* __restrict__ IUw,
                      const float* __restrict__ diag_ku,
                      const int* __restrict__ OFF, const int2* __restrict__ csrPk,
                      float* __restrict__ u_all,
                      float* __restrict__ Lv, float* __restrict__ rs_cm,
                      float* __restrict__ pAp_t,
                      int NNZ, int NLOC, int N, int B0, int B1)
{
  int blk = blockIdx.x;
  float red = 0.f;
  if (blk < B0) {                       // Wm: u_a = hw sum_b (F+F^T)(p_a - p_b)
    int k = blk * TPB + threadIdx.x;
    int wd = *width_p;
    int base = LOC_inInd[k];
    float hw = 0.5f * LOCw[base];
    const int offs[9] = {-1 - wd, -1, -1 + wd, -wd, 0, wd, 1 - wd, 1, 1 + wd};
    float pv[9];
    #pragma unroll
    for (int a = 0; a < 9; ++a) pv[a] = p[base + offs[a]];
    float Fl[81];
    #pragma unroll
    for (int m = 0; m < 81; ++m) Fl[m] = LOC_flows[(size_t)m * NLOC + k];
    float qf = 0.f;
    #pragma unroll
    for (int a = 0; a < 9; ++a) {
      float u = 0.f;
      #pragma unroll
      for (int b = 0; b < 9; ++b) u += (Fl[b * 9 + a] + Fl[a * 9 + b]) * (pv[a] - pv[b]);
      u *= hw;
      u_all[a * NLOC + k] = u;
      qf += u * pv[a];
    }
    red = qf;
  } else if (blk < B1) {                // Wc
    int k = (blk - B0) * TPB + threadIdx.x;
    int r0 = IU_inInd[k];
    float hw = 0.5f * IUw[r0];
    float pr = p[r0];
    float qf = 0.f;
    #pragma unroll
    for (int j = 0; j < 5; ++j) {
      float w = hw * IU_flows[k * 5 + j];
      int c0 = IU_neighInd[k * 5 + j];
      float d = pr - p[c0];
      float uA = w * d;
      u_all[9 * NLOC + j * NLOC + k] = uA;
      u_all[14 * NLOC + j * NLOC + k] = -uA;
      qf += uA * d;
    }
    red = qf;
  } else {                              // CSR: Lv = sum cv (p_i - p_c), rs_cm
    int i = (blk - B1) * TPB + threadIdx.x;
    float pi = p[i];
    int s = OFF[i];
    int e = (i == N - 1) ? NNZ : OFF[i + 1];
    float acc = 0.f, rs = 0.f;
    for (int q = s; q < e; ++q) {
      int2 ed = csrPk[q];
      float cv = __int_as_float(ed.y);
      rs += cv;
      acc += cv * (pi - p[ed.x]);
    }
    Lv[i] = acc;
    rs_cm[i] = rs;
    red = diag_ku[i] * pi * pi + acc * acc;
  }
  float v = blockReduce256(red);
  if (threadIdx.x == 0) atomicAdd(pAp_t, v);
}

// pass 2: Ap = diag p + rs_cm Lv - csc_pull(Lv) + gIdx_pull(u_all); x/r; r.r
__global__ void k_it2(float* __restrict__ x, float* __restrict__ r,
                      const float* __restrict__ p, const float* __restrict__ Lv,
                      const float* __restrict__ rs_cm, const float* __restrict__ diag_ku,
                      const int* __restrict__ OFF,
                      const int2* __restrict__ cscPk,
                      const int* __restrict__ gIdx, const float* __restrict__ u_all,
                      const float* __restrict__ rs_t, const float* __restrict__ pAp_t,
                      float* __restrict__ rs_t1,
                      int NNZ, int NG, int N)
{
  int i = blockIdx.x * TPB + threadIdx.x;
  float alpha = rs_t[0] / pAp_t[0];
  float tg = 0.f;
  {
    int s = OFF[2 * N + i];
    int e = (i == N - 1) ? NG : OFF[2 * N + i + 1];
    for (int q = s; q < e; ++q) tg += u_all[gIdx[q]];
  }
  float sc = 0.f;
  {
    int s = OFF[N + i];
    int e = (i == N - 1) ? NNZ : OFF[N + i + 1];
    for (int q = s; q < e; ++q) {
      int2 ed = cscPk[q];
      sc += __int_as_float(ed.y) * Lv[ed.x];
    }
  }
  float pi = p[i];
  float Ap = diag_ku[i] * pi + rs_cm[i] * Lv[i] - sc + tg;
  x[i] += alpha * pi;
  float rn = r[i] - alpha * Ap;
  r[i] = rn;
  float v = blockReduce256(rn * rn);
  if (threadIdx.x == 0) atomicAdd(rs_t1, v);
}

__global__ void k_it3(float* __restrict__ p, const float* __restrict__ r,
                      const float* __restrict__ rs_new, const float* __restrict__ rs_old, int N)
{
  int i = blockIdx.x * TPB + threadIdx.x;
  float beta = rs_new[0] / rs_old[0];
  p[i] = r[i] + beta * p[i];
}

extern "C" void kernel_launch(void* const* d_in, const int* in_sizes, int n_in,
                              void* d_out, int out_size, void* d_ws, size_t ws_size,
                              hipStream_t stream)
{
  const float* CMw       = (const float*)d_in[0];
  const float* LOCw      = (const float*)d_in[1];
  const float* IUw       = (const float*)d_in[2];
  const float* KUw       = (const float*)d_in[3];
  const float* lmbda     = (const float*)d_in[4];
  const float* kToUconf  = (const float*)d_in[5];
  const float* known     = (const float*)d_in[6];
  const float* kToU      = (const float*)d_in[7];
  const float* Wcm_data  = (const float*)d_in[8];
  const float* LOC_flows = (const float*)d_in[9];
  const float* IU_flows  = (const float*)d_in[10];
  const int*   Wrow      = (const int*)d_in[11];
  const int*   Wcol      = (const int*)d_in[12];
  const int*   LOC_inInd = (const int*)d_in[13];
  const int*   IU_inInd  = (const int*)d_in[14];
  const int*   IU_neighInd = (const int*)d_in[15];
  const int*   width_p   = (const int*)d_in[16];
  const int CG_STEPS = 30;

  const int N    = in_sizes[0];      // 147456 (% 256 == 0)
  const int NNZ  = in_sizes[8];      // 1474560
  const int NLOC = in_sizes[13];     // 73728
  const int NG   = 19 * NLOC;        // 1400832 (> 6N = 884736)

  // ---- workspace layout, ~39.5 MB total (proven budget <= 43.4 MB) ----
  float* x       = (float*)d_out;
  float* r       = (float*)d_ws;                 // N
  float* p       = r + N;                        // N
  float* Lv      = p + N;                        // N
  float* rs_cm   = Lv + N;                       // N
  float* diag_ku = rs_cm + N;                    // N
  int2*  csrPk   = (int2*)(diag_ku + N);         // NNZ int2
  int2*  cscPk   = csrPk + (size_t)NNZ;          // NNZ int2
  int*   gIdx    = (int*)(cscPk + (size_t)NNZ);  // NG
  int*   OFF     = gIdx + (size_t)NG;            // 3N
  // U-region: u_all (NG floats, iteration-only) aliases CNT+CUR (6N, setup-only)
  int*   CNT     = OFF + (size_t)3 * N;          // 3N
  int*   CUR     = CNT + (size_t)3 * N;          // 3N
  float* u_all   = (float*)CNT;                  // NG (covers CNT+CUR and more)
  int*   bsum    = CNT + (size_t)NG;             // 3*(N/256) = 1728
  float* scal    = (float*)(bsum + 3 * (N / TPB));  // 80: rs at [t], pAp at [40+t]

  const int Bn = N / TPB;        // 576
  const int Bz = NNZ / TPB;      // 5760
  const int Bl = NLOC / TPB;     // 288
  const int Z3 = 3 * Bn;

  k_init0<<<Z3, TPB, 0, stream>>>(KUw, kToUconf, lmbda, known, kToU,
                                  diag_ku, r, p, x, CNT, scal, N);
  k_hist<<<Bz + 2 * Bl, TPB, 0, stream>>>(Wrow, Wcol, LOC_inInd, width_p,
                                          IU_inInd, IU_neighInd, CNT,
                                          NLOC, N, Bz, Bz + Bl);
  k_scan1<<<Z3, TPB, 0, stream>>>(CNT, OFF, bsum, 3 * N);
  k_scan2<<<3, 1024, 0, stream>>>(bsum, Bn);
  k_scan3<<<Z3, TPB, 0, stream>>>(OFF, CUR, bsum, 3 * N);
  k_fill<<<Bz + 2 * Bl, TPB, 0, stream>>>(CMw, Wcm_data, Wrow, Wcol,
                                          LOC_inInd, width_p, IU_inInd, IU_neighInd,
                                          CUR, csrPk, cscPk, gIdx,
                                          NLOC, N, Bz, Bz + Bl);

  for (int t = 0; t < CG_STEPS; ++t) {
    k_it1<<<2 * Bl + Bn, TPB, 0, stream>>>(
        p, LOC_flows, LOC_inInd, LOCw, width_p,
        IU_flows, IU_inInd, IU_neighInd, IUw,
        diag_ku, OFF, csrPk, u_all, Lv, rs_cm, scal + 40 + t,
        NNZ, NLOC, N, Bl, 2 * Bl);
    k_it2<<<Bn, TPB, 0, stream>>>(
        x, r, p, Lv, rs_cm, diag_ku, OFF, cscPk, gIdx, u_all,
        scal + t, scal + 40 + t, scal + t + 1, NNZ, NG, N);
    if (t + 1 < CG_STEPS)
      k_it3<<<Bn, TPB, 0, stream>>>(p, r, scal + t + 1, scal + t, N);
  }
}

// Round 7
// 2221.820 us; speedup vs baseline: 1.5461x; 1.1396x over previous
//
#include <hip/hip_runtime.h>

// ---------------------------------------------------------------------------
// MattingSolver CG on MI355X — round 7: R6 + 4-wide MLP unroll on all
// gather loops.
//
// R6 evidence: iterations ~67us/iter with ~5.7M random 4B gathers inside
// avg-10-edge serial row loops -> latency-bound, not byte-bound (byte cuts
// moved 71->67 only). Fix: process 4 edges per step, batching the 4 record
// loads then the 4 dependent gathers -> 4x outstanding misses per lane.
// Setup (k_hist/k_fill) untouched for clean attribution.
//
// Layout (39.5 MB, proven): vecs(5N) | csrPk(NNZ int2) | cscPk(NNZ int2)
//   | gIdx(NG) | OFF(3N) | u_all(NG) aliasing CNT(3N)+CUR(3N) | bsum | scal.
// scal: rs_t at [t], pAp_t at [40+t].
// ---------------------------------------------------------------------------

#define TPB 256

__device__ __forceinline__ float blockReduce256(float v) {
  #pragma unroll
  for (int o = 32; o > 0; o >>= 1) v += __shfl_down(v, o, 64);
  __shared__ float s[4];
  int lane = threadIdx.x & 63, wv = threadIdx.x >> 6;
  if (lane == 0) s[wv] = v;
  __syncthreads();
  return (threadIdx.x == 0) ? (s[0] + s[1] + s[2] + s[3]) : 0.f;
}

// vectors, diag, b, scal, CNT zero, b.b  (grid: 3*Bn)
__global__ void k_init0(const float* __restrict__ KUw, const float* __restrict__ kToUconf,
                        const float* __restrict__ lmbda, const float* __restrict__ known,
                        const float* __restrict__ kToU,
                        float* __restrict__ diag_ku, float* __restrict__ r,
                        float* __restrict__ p, float* __restrict__ x,
                        int* __restrict__ CNT, float* __restrict__ scal, int N)
{
  int i = blockIdx.x * TPB + threadIdx.x;
  if (i < 80) scal[i] = 0.f;
  if (i < 3 * N) CNT[i] = 0;
  float red = 0.f;
  if (i < N) {
    float dk = KUw[i] * kToUconf[i] + lmbda[0] * known[i];
    diag_ku[i] = dk;
    float b = dk * kToU[i];
    r[i] = b; p[i] = b; x[i] = 0.f;
    red = b * b;
  }
  float v = blockReduce256(red);
  if (threadIdx.x == 0) atomicAdd(&scal[0], v);
}

// histograms only (4.35M atomics)  (grid: Bz + 2*Bl)
__global__ void k_hist(const int* __restrict__ Wrow, const int* __restrict__ Wcol,
                       const int* __restrict__ LOC_inInd, const int* __restrict__ width_p,
                       const int* __restrict__ IU_inInd, const int* __restrict__ IU_neighInd,
                       int* __restrict__ CNT,
                       int NLOC, int N, int B0, int B1)
{
  int blk = blockIdx.x;
  if (blk < B0) {
    int e = blk * TPB + threadIdx.x;
    atomicAdd(&CNT[Wrow[e]], 1);
    atomicAdd(&CNT[N + Wcol[e]], 1);
  } else if (blk < B1) {
    int k = (blk - B0) * TPB + threadIdx.x;
    int wd = *width_p;
    int base = LOC_inInd[k];
    const int offs[9] = {-1 - wd, -1, -1 + wd, -wd, 0, wd, 1 - wd, 1, 1 + wd};
    #pragma unroll
    for (int a = 0; a < 9; ++a) atomicAdd(&CNT[2 * N + base + offs[a]], 1);
  } else {
    int k = (blk - B1) * TPB + threadIdx.x;
    int r0 = IU_inInd[k];
    #pragma unroll
    for (int j = 0; j < 5; ++j) {
      atomicAdd(&CNT[2 * N + r0], 1);
      atomicAdd(&CNT[2 * N + IU_neighInd[k * 5 + j]], 1);
    }
  }
}

__global__ void k_scan1(const int* __restrict__ CNT, int* __restrict__ OFF,
                        int* __restrict__ bsum, int tot)
{
  __shared__ int s[TPB];
  int gid = blockIdx.x * TPB + threadIdx.x;
  int v = (gid < tot) ? CNT[gid] : 0;
  s[threadIdx.x] = v;
  __syncthreads();
  #pragma unroll
  for (int o = 1; o < TPB; o <<= 1) {
    int t = (threadIdx.x >= o) ? s[threadIdx.x - o] : 0;
    __syncthreads();
    s[threadIdx.x] += t;
    __syncthreads();
  }
  if (gid < tot) OFF[gid] = s[threadIdx.x] - v;
  if (threadIdx.x == TPB - 1) bsum[blockIdx.x] = s[threadIdx.x];
}

__global__ void k_scan2(int* __restrict__ bsum, int nPerArr)  // 3 blocks x 1024
{
  __shared__ int s[1024];
  int base = blockIdx.x * nPerArr;
  int v = (threadIdx.x < nPerArr) ? bsum[base + threadIdx.x] : 0;
  s[threadIdx.x] = v;
  __syncthreads();
  for (int o = 1; o < 1024; o <<= 1) {
    int t = (threadIdx.x >= o) ? s[threadIdx.x - o] : 0;
    __syncthreads();
    s[threadIdx.x] += t;
    __syncthreads();
  }
  if (threadIdx.x < nPerArr) bsum[base + threadIdx.x] = s[threadIdx.x] - v;
}

__global__ void k_scan3(int* __restrict__ OFF, int* __restrict__ CUR,
                        const int* __restrict__ bsum, int tot)
{
  int gid = blockIdx.x * TPB + threadIdx.x;
  if (gid < tot) {
    int o = OFF[gid] + bsum[blockIdx.x];
    OFF[gid] = o;
    CUR[gid] = o;
  }
}

// fill packed CSR/CSC and gather-index list  (grid: Bz + 2*Bl)
__global__ void k_fill(const float* __restrict__ CMw, const float* __restrict__ Wcm_data,
                       const int* __restrict__ Wrow, const int* __restrict__ Wcol,
                       const int* __restrict__ LOC_inInd, const int* __restrict__ width_p,
                       const int* __restrict__ IU_inInd, const int* __restrict__ IU_neighInd,
                       int* __restrict__ CUR,
                       int2* __restrict__ csrPk, int2* __restrict__ cscPk,
                       int* __restrict__ gIdx,
                       int NLOC, int N, int B0, int B1)
{
  int blk = blockIdx.x;
  if (blk < B0) {
    int e = blk * TPB + threadIdx.x;
    int row = Wrow[e], col = Wcol[e];
    int cv = __float_as_int(CMw[row] * Wcm_data[e]);
    int pr = atomicAdd(&CUR[row], 1);
    csrPk[pr] = make_int2(col, cv);
    int pc = atomicAdd(&CUR[N + col], 1);
    cscPk[pc] = make_int2(row, cv);
  } else if (blk < B1) {
    int k = (blk - B0) * TPB + threadIdx.x;
    int wd = *width_p;
    int base = LOC_inInd[k];
    const int offs[9] = {-1 - wd, -1, -1 + wd, -wd, 0, wd, 1 - wd, 1, 1 + wd};
    #pragma unroll
    for (int a = 0; a < 9; ++a) {
      int pos = atomicAdd(&CUR[2 * N + base + offs[a]], 1);
      gIdx[pos] = a * NLOC + k;
    }
  } else {
    int k = (blk - B1) * TPB + threadIdx.x;
    int r0 = IU_inInd[k];
    #pragma unroll
    for (int j = 0; j < 5; ++j) {
      int c0 = IU_neighInd[k * 5 + j];
      int p1 = atomicAdd(&CUR[2 * N + r0], 1);
      gIdx[p1] = 9 * NLOC + j * NLOC + k;    // +w(p_r0 - p_c0) -> row r0
      int p2 = atomicAdd(&CUR[2 * N + c0], 1);
      gIdx[p2] = 14 * NLOC + j * NLOC + k;   // -w(p_r0 - p_c0) -> row c0
    }
  }
}

// pass 1: Wm/Wc products -> u_all (natural layout); CSR Lv/rs_cm; full pAp
// grid: Bl + Bl + Bn
__global__ void k_it1(const float* __restrict__ p,
                      const float* __restrict__ LOC_flows, const int* __restrict__ LOC_inInd,
                      const float* __restrict__ LOCw, const int* __restrict__ width_p,
                      const float* __restrict__ IU_flows, const int* __restrict__ IU_inInd,
                      const int* __restrict__ IU_neighInd, const float* __restrict__ IUw,
                      const float* __restrict__ diag_ku,
                      const int* __restrict__ OFF, const int2* __restrict__ csrPk,
                      float* __restrict__ u_all,
                      float* __restrict__ Lv, float* __restrict__ rs_cm,
                      float* __restrict__ pAp_t,
                      int NNZ, int NLOC, int N, int B0, int B1)
{
  int blk = blockIdx.x;
  float red = 0.f;
  if (blk < B0) {                       // Wm: u_a = hw sum_b (F+F^T)(p_a - p_b)
    int k = blk * TPB + threadIdx.x;
    int wd = *width_p;
    int base = LOC_inInd[k];
    float hw = 0.5f * LOCw[base];
    const int offs[9] = {-1 - wd, -1, -1 + wd, -wd, 0, wd, 1 - wd, 1, 1 + wd};
    float pv[9];
    #pragma unroll
    for (int a = 0; a < 9; ++a) pv[a] = p[base + offs[a]];
    float Fl[81];
    #pragma unroll
    for (int m = 0; m < 81; ++m) Fl[m] = LOC_flows[(size_t)m * NLOC + k];
    float qf = 0.f;
    #pragma unroll
    for (int a = 0; a < 9; ++a) {
      float u = 0.f;
      #pragma unroll
      for (int b = 0; b < 9; ++b) u += (Fl[b * 9 + a] + Fl[a * 9 + b]) * (pv[a] - pv[b]);
      u *= hw;
      u_all[a * NLOC + k] = u;
      qf += u * pv[a];
    }
    red = qf;
  } else if (blk < B1) {                // Wc
    int k = (blk - B0) * TPB + threadIdx.x;
    int r0 = IU_inInd[k];
    float hw = 0.5f * IUw[r0];
    float pr = p[r0];
    // batch the 5 neighbor-index loads, then the 5 gathers
    int c[5]; float w[5];
    #pragma unroll
    for (int j = 0; j < 5; ++j) {
      c[j] = IU_neighInd[k * 5 + j];
      w[j] = hw * IU_flows[k * 5 + j];
    }
    float pc[5];
    #pragma unroll
    for (int j = 0; j < 5; ++j) pc[j] = p[c[j]];
    float qf = 0.f;
    #pragma unroll
    for (int j = 0; j < 5; ++j) {
      float d = pr - pc[j];
      float uA = w[j] * d;
      u_all[9 * NLOC + j * NLOC + k] = uA;
      u_all[14 * NLOC + j * NLOC + k] = -uA;
      qf += uA * d;
    }
    red = qf;
  } else {                              // CSR: Lv = sum cv (p_i - p_c), 4-wide MLP
    int i = (blk - B1) * TPB + threadIdx.x;
    float pi = p[i];
    int s = OFF[i];
    int e = (i == N - 1) ? NNZ : OFF[i + 1];
    float acc = 0.f, rs = 0.f;
    int q = s;
    for (; q + 4 <= e; q += 4) {
      int2 e0 = csrPk[q];
      int2 e1 = csrPk[q + 1];
      int2 e2 = csrPk[q + 2];
      int2 e3 = csrPk[q + 3];
      float g0 = p[e0.x], g1 = p[e1.x], g2 = p[e2.x], g3 = p[e3.x];
      float c0 = __int_as_float(e0.y), c1 = __int_as_float(e1.y);
      float c2 = __int_as_float(e2.y), c3 = __int_as_float(e3.y);
      rs += (c0 + c1) + (c2 + c3);
      acc += c0 * (pi - g0) + c1 * (pi - g1) + c2 * (pi - g2) + c3 * (pi - g3);
    }
    for (; q < e; ++q) {
      int2 ed = csrPk[q];
      float cv = __int_as_float(ed.y);
      rs += cv;
      acc += cv * (pi - p[ed.x]);
    }
    Lv[i] = acc;
    rs_cm[i] = rs;
    red = diag_ku[i] * pi * pi + acc * acc;
  }
  float v = blockReduce256(red);
  if (threadIdx.x == 0) atomicAdd(pAp_t, v);
}

// pass 2: Ap = diag p + rs_cm Lv - csc_pull(Lv) + gIdx_pull(u_all); x/r; r.r
// 4-wide MLP on both pull loops.
__global__ void k_it2(float* __restrict__ x, float* __restrict__ r,
                      const float* __restrict__ p, const float* __restrict__ Lv,
                      const float* __restrict__ rs_cm, const float* __restrict__ diag_ku,
                      const int* __restrict__ OFF,
                      const int2* __restrict__ cscPk,
                      const int* __restrict__ gIdx, const float* __restrict__ u_all,
                      const float* __restrict__ rs_t, const float* __restrict__ pAp_t,
                      float* __restrict__ rs_t1,
                      int NNZ, int NG, int N)
{
  int i = blockIdx.x * TPB + threadIdx.x;
  float alpha = rs_t[0] / pAp_t[0];
  float tg = 0.f;
  {
    int s = OFF[2 * N + i];
    int e = (i == N - 1) ? NG : OFF[2 * N + i + 1];
    int q = s;
    for (; q + 4 <= e; q += 4) {
      int g0 = gIdx[q], g1 = gIdx[q + 1], g2 = gIdx[q + 2], g3 = gIdx[q + 3];
      float u0 = u_all[g0], u1 = u_all[g1], u2 = u_all[g2], u3 = u_all[g3];
      tg += (u0 + u1) + (u2 + u3);
    }
    for (; q < e; ++q) tg += u_all[gIdx[q]];
  }
  float sc = 0.f;
  {
    int s = OFF[N + i];
    int e = (i == N - 1) ? NNZ : OFF[N + i + 1];
    int q = s;
    for (; q + 4 <= e; q += 4) {
      int2 e0 = cscPk[q];
      int2 e1 = cscPk[q + 1];
      int2 e2 = cscPk[q + 2];
      int2 e3 = cscPk[q + 3];
      float l0 = Lv[e0.x], l1 = Lv[e1.x], l2 = Lv[e2.x], l3 = Lv[e3.x];
      sc += __int_as_float(e0.y) * l0 + __int_as_float(e1.y) * l1
          + __int_as_float(e2.y) * l2 + __int_as_float(e3.y) * l3;
    }
    for (; q < e; ++q) {
      int2 ed = cscPk[q];
      sc += __int_as_float(ed.y) * Lv[ed.x];
    }
  }
  float pi = p[i];
  float Ap = diag_ku[i] * pi + rs_cm[i] * Lv[i] - sc + tg;
  x[i] += alpha * pi;
  float rn = r[i] - alpha * Ap;
  r[i] = rn;
  float v = blockReduce256(rn * rn);
  if (threadIdx.x == 0) atomicAdd(rs_t1, v);
}

__global__ void k_it3(float* __restrict__ p, const float* __restrict__ r,
                      const float* __restrict__ rs_new, const float* __restrict__ rs_old, int N)
{
  int i = blockIdx.x * TPB + threadIdx.x;
  float beta = rs_new[0] / rs_old[0];
  p[i] = r[i] + beta * p[i];
}

extern "C" void kernel_launch(void* const* d_in, const int* in_sizes, int n_in,
                              void* d_out, int out_size, void* d_ws, size_t ws_size,
                              hipStream_t stream)
{
  const float* CMw       = (const float*)d_in[0];
  const float* LOCw      = (const float*)d_in[1];
  const float* IUw       = (const float*)d_in[2];
  const float* KUw       = (const float*)d_in[3];
  const float* lmbda     = (const float*)d_in[4];
  const float* kToUconf  = (const float*)d_in[5];
  const float* known     = (const float*)d_in[6];
  const float* kToU      = (const float*)d_in[7];
  const float* Wcm_data  = (const float*)d_in[8];
  const float* LOC_flows = (const float*)d_in[9];
  const float* IU_flows  = (const float*)d_in[10];
  const int*   Wrow      = (const int*)d_in[11];
  const int*   Wcol      = (const int*)d_in[12];
  const int*   LOC_inInd = (const int*)d_in[13];
  const int*   IU_inInd  = (const int*)d_in[14];
  const int*   IU_neighInd = (const int*)d_in[15];
  const int*   width_p   = (const int*)d_in[16];
  const int CG_STEPS = 30;

  const int N    = in_sizes[0];      // 147456 (% 256 == 0)
  const int NNZ  = in_sizes[8];      // 1474560
  const int NLOC = in_sizes[13];     // 73728
  const int NG   = 19 * NLOC;        // 1400832 (> 6N = 884736)

  // ---- workspace layout, ~39.5 MB (proven budget) ----
  float* x       = (float*)d_out;
  float* r       = (float*)d_ws;                 // N
  float* p       = r + N;                        // N
  float* Lv      = p + N;                        // N
  float* rs_cm   = Lv + N;                       // N
  float* diag_ku = rs_cm + N;                    // N
  int2*  csrPk   = (int2*)(diag_ku + N);         // NNZ int2
  int2*  cscPk   = csrPk + (size_t)NNZ;          // NNZ int2
  int*   gIdx    = (int*)(cscPk + (size_t)NNZ);  // NG
  int*   OFF     = gIdx + (size_t)NG;            // 3N
  int*   CNT     = OFF + (size_t)3 * N;          // 3N (setup only)
  int*   CUR     = CNT + (size_t)3 * N;          // 3N (setup only)
  float* u_all   = (float*)CNT;                  // NG floats, aliases CNT+CUR
  int*   bsum    = CNT + (size_t)NG;             // 3*(N/256)
  float* scal    = (float*)(bsum + 3 * (N / TPB));  // 80 floats

  const int Bn = N / TPB;        // 576
  const int Bz = NNZ / TPB;      // 5760
  const int Bl = NLOC / TPB;     // 288
  const int Z3 = 3 * Bn;

  k_init0<<<Z3, TPB, 0, stream>>>(KUw, kToUconf, lmbda, known, kToU,
                                  diag_ku, r, p, x, CNT, scal, N);
  k_hist<<<Bz + 2 * Bl, TPB, 0, stream>>>(Wrow, Wcol, LOC_inInd, width_p,
                                          IU_inInd, IU_neighInd, CNT,
                                          NLOC, N, Bz, Bz + Bl);
  k_scan1<<<Z3, TPB, 0, stream>>>(CNT, OFF, bsum, 3 * N);
  k_scan2<<<3, 1024, 0, stream>>>(bsum, Bn);
  k_scan3<<<Z3, TPB, 0, stream>>>(OFF, CUR, bsum, 3 * N);
  k_fill<<<Bz + 2 * Bl, TPB, 0, stream>>>(CMw, Wcm_data, Wrow, Wcol,
                                          LOC_inInd, width_p, IU_inInd, IU_neighInd,
                                          CUR, csrPk, cscPk, gIdx,
                                          NLOC, N, Bz, Bz + Bl);

  for (int t = 0; t < CG_STEPS; ++t) {
    k_it1<<<2 * Bl + Bn, TPB, 0, stream>>>(
        p, LOC_flows, LOC_inInd, LOCw, width_p,
        IU_flows, IU_inInd, IU_neighInd, IUw,
        diag_ku, OFF, csrPk, u_all, Lv, rs_cm, scal + 40 + t,
        NNZ, NLOC, N, Bl, 2 * Bl);
    k_it2<<<Bn, TPB, 0, stream>>>(
        x, r, p, Lv, rs_cm, diag_ku, OFF, cscPk, gIdx, u_all,
        scal + t, scal + 40 + t, scal + t + 1, NNZ, NG, N);
    if (t + 1 < CG_STEPS)
      k_it3<<<Bn, TPB, 0, stream>>>(p, r, scal + t + 1, scal + t, N);
  }
}